// Round 3
// baseline (247.993 us; speedup 1.0000x reference)
//
#include <hip/hip_runtime.h>

#define H 360
#define W 720
#define NB 8
#define XC 3
#define YC 10
#define TX 240
#define TY 36
#define BPB (XC*YC)             // 30 blocks per batch
#define WR 52                   // window rows: gi = by-8+r, r in 0..51
#define LST 260                 // LDS row stride (floats): 256 cols + 4 pad
#define LSZ (WR*LST)            // one window buffer (floats)
#define DTS 600.0f
#define REARTH 6371000.0f
#define D2R 0.017453292519943295f

#define NQ1 (WR*64)             // 3328 preamble quads
#define NHALO 1168              // rows{0..7,44..51}x64 + rows 8..43 x quads{0,1,62,63}
#define NGROUPS 5               // 5 groups x (2 fused pairs = 4 steps) = 20 steps
#define FLAG_STRIDE 32          // 128 B per flag line

// Round 3: substep PAIRING. Each wave reads a 14-row window once and computes
// TWO timesteps in registers (4-deep line sweep: T->h->T'->h'->T''), writing
// only the t+2 rows. Halves LDS read phases (20->10), writes (24->12 rows/
// group) and barriers (20->10) at +29% register-resident VALU (proven ~free
// in R2). Valid-row accounting: pair A out rows 4..47 (<- rows 0..51), pair B
// out rows 8..43 (<- 4..47); stale rows 0..3/48..51 feed only dead outputs.

// LLC-coherent 8B load/store (agent-scope relaxed atomic -> dwordx2 sc1)
static __device__ __forceinline__ float2 ldc8(const float* p) {
    unsigned long long u = __hip_atomic_load((const unsigned long long*)p,
                                             __ATOMIC_RELAXED, __HIP_MEMORY_SCOPE_AGENT);
    return __builtin_bit_cast(float2, u);
}
static __device__ __forceinline__ void stc8(float* p, float2 v) {
    __hip_atomic_store((unsigned long long*)p, __builtin_bit_cast(unsigned long long, v),
                       __ATOMIC_RELAXED, __HIP_MEMORY_SCOPE_AGENT);
}

// DPP wave-wide lane shifts on the VALU pipe (bound_ctrl=1: shifted-in lanes
// read 0 — lands only in window cols 0/255, the unconsumed degraded halo).
static __device__ __forceinline__ float dpp_up1(float x) {   // lane i <- lane i-1
    return __builtin_bit_cast(float, __builtin_amdgcn_update_dpp(
        0, __builtin_bit_cast(int, x), 0x138 /*wave_shr:1*/, 0xF, 0xF, true));
}
static __device__ __forceinline__ float dpp_dn1(float x) {   // lane i <- lane i+1
    return __builtin_bit_cast(float, __builtin_amdgcn_update_dpp(
        0, __builtin_bit_cast(int, x), 0x130 /*wave_shl:1*/, 0xF, 0xF, true));
}

__global__ __launch_bounds__(512, 2) void ocean_persist(
    const float* __restrict__ Tin, const float* __restrict__ ug,
    const float* __restrict__ vg, const float* __restrict__ lat,
    const float* __restrict__ lon, const float* __restrict__ mask,
    float* __restrict__ out, float* __restrict__ wsf, int* __restrict__ flags)
{
    // Double-buffered window: pair A reads buf0 writes buf1; pair B reads
    // buf1 writes buf0. Group always ends in buf0; import lands in buf0.
    __shared__ float sT[2 * LSZ];

    const int tid = threadIdx.x;
    const int b  = blockIdx.z;
    const int bx = blockIdx.x * TX;
    const int by = blockIdx.y * TY;
    const int plane = H * W;

    const float dlat = lat[1] - lat[0];               // -0.5
    const float dy   = REARTH * D2R * fabsf(dlat);
    const float sgn  = (dlat > 0.f) ? 1.f : -1.f;
    const float dlon = lon[1] - lon[0];
    const float i2dy = 0.5f / dy, i1dy = 1.f / dy;

    const float* Tb = Tin + b * plane;
    const float* ub = ug  + b * plane;
    const float* vb = vg  + b * plane;
    float* outb = out + b * plane;
    float* wsb  = wsf + b * plane;

    int* bflags = flags + b * BPB * FLAG_STRIDE;
    int* myflag = bflags + (blockIdx.y * XC + blockIdx.x) * FLAG_STRIDE;

    // ---------- strip mapping: wave = 6-row group, 8 waves ----------
    const int cq = tid & 63;             // col quad 0..63 (window cols 0..255)
    const int rg = tid >> 6;             // row group 0..7 (== wave id)
    const int c0 = cq << 2;
    const int n0 = 6 * rg + 4;           // first out row (window row index)
    const int a1 = 6 * rg + 1;           // first h row (k=0): rows a1..a1+11
    const int gj0 = (bx - 8 + c0 + W) % W;
    const bool hlzb = (gj0 == 0);            // filter zero-pad left of gj=0
    const bool hrzb = (gj0 + 3 == W - 1);    // filter zero-pad right of gj=W-1
    const bool topB = (blockIdx.y == 0), botB = (blockIdx.y == YC - 1);
    const bool topP = topB && (rg == 0);     // in-register clamp patches
    const bool botP = botB && (rg == 6);

    // ---------- bake invariants ----------
    int goff1[7], lds1o[7];              // preamble quads
    #pragma unroll
    for (int k = 0; k < 7; ++k) {
        const int q = tid + 512 * k;
        if (q < NQ1) {
            const int r = q >> 6, cc0 = (q & 63) << 2;
            int gi = min(max(by - 8 + r, 0), H - 1);
            const int gj = (bx - 8 + cc0 + W) % W;
            goff1[k] = gi * W + gj;
            lds1o[k] = r * LST + cc0;
        } else goff1[k] = -1;
    }

    int hgo[3], hlo[3];                  // halo import quads (3/thread)
    #pragma unroll
    for (int t = 0; t < 3; ++t) {
        const int q = tid + 512 * t;
        if (q < NHALO) {
            int r, cc0;
            if (q < 1024) { const int ri = q >> 6; r = (ri < 8) ? ri : 36 + ri; cc0 = (q & 63) << 2; }
            else { const int u = q - 1024; r = 8 + (u >> 2); const int qi = u & 3;
                   cc0 = (qi < 2) ? (qi << 2) : (248 + ((qi - 2) << 2)); }
            int gi = min(max(by - 8 + r, 0), H - 1);
            const int gj = (bx - 8 + cc0 + W) % W;
            hgo[t] = gi * W + gj;
            hlo[t] = r * LST + cc0;
        } else hgo[t] = -1;
    }

    // advection coeffs for the 12 h rows a1..a1+11 (shared by both stages)
    float cuA[12][4], cvA[12][4];
    unsigned domm = 0;
    #pragma unroll
    for (int k = 0; k < 12; ++k) {
        #pragma unroll
        for (int t = 0; t < 4; ++t) { cuA[k][t] = 0.f; cvA[k][t] = 0.f; }
        const int gi = by - 8 + a1 + k;
        if ((unsigned)gi < H) {
            const float dxv  = REARTH * D2R * dlon * cosf(lat[gi] * D2R);
            const float rdx2 = 0.5f / dxv;
            const float ivy  = (gi == 0 || gi == H - 1) ? i1dy : i2dy;
            #pragma unroll
            for (int t = 0; t < 4; ++t) {
                const int off = gi * W + gj0 + t;
                const float mk = mask[off];
                cuA[k][t] = -DTS * mk * ub[off] * rdx2;
                cvA[k][t] = -DTS * mk * vb[off] * sgn * ivy;
            }
            domm |= 1u << k;
        }
    }

    // mask/16 for the 10 filter-output rows a1+1..a1+10 (shared by both stages)
    float m16A[10][4];
    #pragma unroll
    for (int m = 0; m < 10; ++m) {
        const int gi = by - 8 + 6 * rg + 2 + m;
        #pragma unroll
        for (int t = 0; t < 4; ++t)
            m16A[m][t] = ((unsigned)gi < H) ? mask[gi * W + gj0 + t] * (1.f / 16.f) : 0.f;
    }

    // out-row masks: n = n0+i, i = 0..5
    unsigned outmA = 0, outmB = 0, tilem = 0, ringm = 0;
    #pragma unroll
    for (int i = 0; i < 6; ++i) {
        const int n = n0 + i;
        const int gi = by - 8 + n;
        if (n <= 47 && (unsigned)gi < H) outmA |= 1u << i;   // pair A: rows 4..47
        if (n >= 8 && n <= 43)           outmB |= 1u << i;   // pair B: tile rows
        const bool inTile = (n >= 8 && n <= 43 && cq >= 2 && cq <= 61);
        if (inTile) {
            tilem |= 1u << i;
            if (n <= 15 || n >= 36 || cq <= 3 || cq >= 60) ringm |= 1u << i;
        }
    }
    const int obase = (by - 8 + n0) * W + bx + c0 - 8;   // global offset of row n0
    const int wbase = n0 * LST + c0;                     // LDS write base
    const int rbase = 6 * rg * LST + c0;                 // LDS read base (row n0-4)
    const int rtop  = 51 * LST + c0;                     // clamp for rg7 reads

    // neighbor flag pointers (8-neighborhood; x wraps, y clamps to self)
    const int* nbrF = myflag;
    if (tid < 8) {
        int dyn, dxn;
        if (tid < 3)      { dyn = -1; dxn = tid - 1; }
        else if (tid == 3){ dyn = 0;  dxn = -1; }
        else if (tid == 4){ dyn = 0;  dxn = 1; }
        else              { dyn = 1;  dxn = tid - 6; }
        const int ny = (int)blockIdx.y + dyn;
        const int nx = ((int)blockIdx.x + dxn + XC) % XC;
        if (ny >= 0 && ny < YC) nbrF = bflags + (ny * XC + nx) * FLAG_STRIDE;
    }

    // ---------- preamble: full window -> BOTH buffers ----------
    #pragma unroll
    for (int k = 0; k < 7; ++k)
        if (goff1[k] >= 0) {
            const float4 v = *(const float4*)(Tb + goff1[k]);
            *(float4*)(sT + lds1o[k])       = v;
            *(float4*)(sT + LSZ + lds1o[k]) = v;
        }
    __syncthreads();

    // advect + horizontal filter for coeff row k (compile-time k)
    auto Hrow = [&](int k, const float4& m1, const float4& cc, const float4& vD) -> float4 {
        const float tl = dpp_up1(cc.w);
        const float tr = dpp_dn1(cc.x);
        const bool dj = (domm >> k) & 1;
        float4 o;
        o.x = (dj ? cc.x : 0.f) + cuA[k][0]*(cc.y - tl)   + cvA[k][0]*(vD.x - m1.x);
        o.y = (dj ? cc.y : 0.f) + cuA[k][1]*(cc.z - cc.x) + cvA[k][1]*(vD.y - m1.y);
        o.z = (dj ? cc.z : 0.f) + cuA[k][2]*(cc.w - cc.y) + cvA[k][2]*(vD.z - m1.z);
        o.w = (dj ? cc.w : 0.f) + cuA[k][3]*(tr   - cc.z) + cvA[k][3]*(vD.w - m1.w);
        float hl = dpp_up1(o.w);
        float hr = dpp_dn1(o.x);
        if (hlzb) hl = 0.f;
        if (hrzb) hr = 0.f;
        float4 r;
        r.x = hl  + 2.f*o.x + o.y;
        r.y = o.x + 2.f*o.y + o.z;
        r.z = o.y + 2.f*o.z + o.w;
        r.w = o.z + 2.f*o.w + hr;
        return r;
    };
    // vertical filter + mask for m16 row m (compile-time m)
    auto Vrow = [&](int m, const float4& a_, const float4& b_, const float4& c_) -> float4 {
        float4 r;
        r.x = (a_.x + 2.f*b_.x + c_.x) * m16A[m][0];
        r.y = (a_.y + 2.f*b_.y + c_.y) * m16A[m][1];
        r.z = (a_.z + 2.f*b_.z + c_.z) * m16A[m][2];
        r.w = (a_.w + 2.f*b_.w + c_.w) * m16A[m][3];
        return r;
    };

    // ---------- fused 2-step pair: read cur once, 4-deep line sweep ----------
    auto pair2 = [&](const float* cur, float* nxt, bool isA, bool finalOut, float* ring) {
        const unsigned wm = isA ? outmA : outmB;
        float4 z4; z4.x = z4.y = z4.z = z4.w = 0.f;
        float4 t0 = z4, t1 = z4, h0 = z4, h1 = z4, p0 = z4, p1 = z4, q0 = z4, q1 = z4;
        #pragma unroll
        for (int s = 0; s < 14; ++s) {
            const int off = min(rbase + s * LST, rtop);   // clamp only bites rg7
            const float4 tn = *(const float4*)(cur + off);
            float4 hn = z4, pn = z4, qn = z4;
            if (s >= 2) hn = Hrow(s - 2, t0, t1, tn);          // h row a1+s-2
            if (s >= 4) pn = Vrow(s - 4, h0, h1, hn);          // T' row n0-2+(s-4)
            if (s >= 6) {
                const int k2 = s - 6;                           // h' row a1+2+k2
                float4 m1q = p0, vDq = pn;
                if (topP && k2 == 5) m1q = p1;   // T'(row7) := T'(row8) clamp
                if (botP && k2 == 4) vDq = p1;   // T'(row44) := T'(row43) clamp
                qn = Hrow(k2 + 2, m1q, p1, vDq);
            }
            if (s >= 8) {
                const int i = s - 8;                            // out row n0+i
                const float4 o = Vrow(i + 2, q0, q1, qn);
                if (!finalOut) {
                    if ((wm >> i) & 1)
                        *(float4*)(nxt + wbase + i * LST) = o;
                    if (isA) {   // fresh clamp-replica rows for pair B's stage A
                        if (topP && i == 4) *(float4*)(nxt + 7  * LST + c0) = o; // row7 <- row8
                        if (botB && rg == 6 && i == 3)
                                            *(float4*)(nxt + 44 * LST + c0) = o; // row44 <- row43
                    }
                } else if ((tilem >> i) & 1) {
                    *(float4*)(outb + obase + i * W) = o;
                }
                if (ring && ((ringm >> i) & 1)) {
                    float2 lo; lo.x = o.x; lo.y = o.y;
                    float2 hi; hi.x = o.z; hi.y = o.w;
                    stc8(ring + obase + i * W, lo);
                    stc8(ring + obase + i * W + 2, hi);
                }
            }
            t0 = t1; t1 = tn;
            if (s >= 2) { h0 = h1; h1 = hn; }
            if (s >= 4) { p0 = p1; p1 = pn; }
            if (s >= 6) { q0 = q1; q1 = qn; }
        }
    };

    // ---------- 5 groups x 2 pairs ----------
    #pragma unroll 1
    for (int g = 0; g < NGROUPS; ++g) {
        if (g) {
            __syncthreads();   // drains ring stores (per-wave vmcnt0 before s_barrier)
            if (tid == 0)
                __hip_atomic_store(myflag, g, __ATOMIC_RELAXED, __HIP_MEMORY_SCOPE_AGENT);
            if (tid < 64) {    // wave 0, lanes 0..7 poll the 8 neighbors
                long long t0c = (long long)clock64();
                for (;;) {
                    const int v = (tid < 8)
                        ? __hip_atomic_load(nbrF, __ATOMIC_RELAXED, __HIP_MEMORY_SCOPE_AGENT)
                        : 0x7fffffff;
                    if (__all(v >= g)) break;
                    __builtin_amdgcn_s_sleep(1);
                    if ((long long)clock64() - t0c > 200000000LL) break;  // no-hang bailout
                }
            }
            __syncthreads();
            // halo import (depth 8) from ring(g-1): g-1 even -> outb, odd -> wsb
            const float* prev = ((g - 1) & 1) ? wsb : outb;
            #pragma unroll
            for (int t = 0; t < 3; ++t) {
                if (hgo[t] >= 0) {
                    const float2 lo = ldc8(prev + hgo[t]);
                    const float2 hi = ldc8(prev + hgo[t] + 2);
                    float4 v; v.x = lo.x; v.y = lo.y; v.z = hi.x; v.w = hi.y;
                    *(float4*)(sT + hlo[t]) = v;   // buf0 = current data buffer
                }
            }
            __syncthreads();
        }
        const bool lastG = (g == NGROUPS - 1);
        float* ringp = lastG ? nullptr : ((g & 1) ? wsb : outb);   // ring(g)
        pair2(sT, sT + LSZ, true, false, nullptr);       // steps 1,2 -> buf1
        __syncthreads();
        pair2(sT + LSZ, sT, false, lastG, ringp);        // steps 3,4 -> buf0/out
        __syncthreads();
    }
}

extern "C" void kernel_launch(void* const* d_in, const int* in_sizes, int n_in,
                              void* d_out, int out_size, void* d_ws, size_t ws_size,
                              hipStream_t stream)
{
    const float* T    = (const float*)d_in[0];
    const float* ug   = (const float*)d_in[1];
    const float* vg   = (const float*)d_in[2];
    const float* lat  = (const float*)d_in[3];
    const float* lon  = (const float*)d_in[4];
    const float* mask = (const float*)d_in[5];
    float* out = (float*)d_out;

    int*   flags = (int*)d_ws;                        // 8 x 30 flags @ 128 B
    float* wsf   = (float*)((char*)d_ws + 65536);     // odd-group ring buffer

    hipMemsetAsync(d_ws, 0, 65536, stream);

    ocean_persist<<<dim3(XC, YC, NB), dim3(512), 0, stream>>>(
        T, ug, vg, lat, lon, mask, out, wsf, flags);
}

// Round 4
// 181.624 us; speedup vs baseline: 1.3654x; 1.3654x over previous
//
#include <hip/hip_runtime.h>

#define H 360
#define W 720
#define NB 8
#define XC 3
#define YC 20
#define TX 240
#define TY 18
#define BPB (XC*YC)             // 60 blocks per batch
#define WR 34                   // window rows: gi = by-8+r, r in 0..33
#define LST 260                 // LDS row stride (floats): 256 cols + 4 pad
#define LSZ (WR*LST)            // one window buffer (floats)
#define DTS 600.0f
#define REARTH 6371000.0f
#define D2R 0.017453292519943295f

#define NQ1 (WR*64)             // 2176 preamble quads
#define NHALO 1096              // rows{0..7,26..33}x64 + rows 8..25 x quads{0,1,62,63}
#define NGROUPS 5               // 5 groups x 4 substeps = 20 steps
#define FLAG_STRIDE 32          // 128 B per flag line

// Round 4: TWO INDEPENDENT BLOCKS PER CU. R2 proved same-block waves can't
// fill convoy stalls (they share the barrier). YC 10->20: WR=34 window,
// 70.7 KB dbl-buffered LDS -> 2 blocks/CU; grid 480 <= 512 residency cap
// (flag protocol needs co-residency). 8 waves x 4-row pitch, <=128 VGPR.

// LLC-coherent 8B load/store (agent-scope relaxed atomic -> dwordx2 sc1)
static __device__ __forceinline__ float2 ldc8(const float* p) {
    unsigned long long u = __hip_atomic_load((const unsigned long long*)p,
                                             __ATOMIC_RELAXED, __HIP_MEMORY_SCOPE_AGENT);
    return __builtin_bit_cast(float2, u);
}
static __device__ __forceinline__ void stc8(float* p, float2 v) {
    __hip_atomic_store((unsigned long long*)p, __builtin_bit_cast(unsigned long long, v),
                       __ATOMIC_RELAXED, __HIP_MEMORY_SCOPE_AGENT);
}

// DPP wave-wide lane shifts on the VALU pipe (bound_ctrl=1: shifted-in lanes
// read 0 — lands only in window cols 0/255, the unconsumed degraded halo).
static __device__ __forceinline__ float dpp_up1(float x) {   // lane i <- lane i-1
    return __builtin_bit_cast(float, __builtin_amdgcn_update_dpp(
        0, __builtin_bit_cast(int, x), 0x138 /*wave_shr:1*/, 0xF, 0xF, true));
}
static __device__ __forceinline__ float dpp_dn1(float x) {   // lane i <- lane i+1
    return __builtin_bit_cast(float, __builtin_amdgcn_update_dpp(
        0, __builtin_bit_cast(int, x), 0x130 /*wave_shl:1*/, 0xF, 0xF, true));
}

__global__ __launch_bounds__(512, 4) void ocean_persist(
    const float* __restrict__ Tin, const float* __restrict__ ug,
    const float* __restrict__ vg, const float* __restrict__ lat,
    const float* __restrict__ lon, const float* __restrict__ mask,
    float* __restrict__ out, float* __restrict__ wsf, int* __restrict__ flags)
{
    // Double-buffered window: substep reads buf p, writes buf p^1 ->
    // one barrier per substep. Group parity ends in buf0; import -> buf0.
    __shared__ float sT[2 * LSZ];

    const int tid = threadIdx.x;
    const int b  = blockIdx.z;
    const int bx = blockIdx.x * TX;
    const int by = blockIdx.y * TY;
    const int plane = H * W;

    const float dlat = lat[1] - lat[0];               // -0.5
    const float dy   = REARTH * D2R * fabsf(dlat);
    const float sgn  = (dlat > 0.f) ? 1.f : -1.f;
    const float dlon = lon[1] - lon[0];
    const float i2dy = 0.5f / dy, i1dy = 1.f / dy;

    const float* Tb = Tin + b * plane;
    const float* ub = ug  + b * plane;
    const float* vb = vg  + b * plane;
    float* outb = out + b * plane;
    float* wsb  = wsf + b * plane;

    int* bflags = flags + b * BPB * FLAG_STRIDE;
    int* myflag = bflags + (blockIdx.y * XC + blockIdx.x) * FLAG_STRIDE;

    // ---------- strip mapping: 8 waves x 4-row output pitch ----------
    const int cq = tid & 63;             // col quad 0..63 (window cols 0..255)
    const int rg = tid >> 6;             // row group 0..7 (== wave id)
    const int c0 = cq << 2;
    const int a  = 1 + 4 * rg;           // first h row; h rows a..a+5 (j<6)
    const int gj0 = (bx - 8 + c0 + W) % W;
    const bool hlzb = (gj0 == 0);            // filter zero-pad left of gj=0
    const bool hrzb = (gj0 + 3 == W - 1);    // filter zero-pad right of gj=W-1
    const bool topB = (blockIdx.y == 0), botB = (blockIdx.y == YC - 1);

    // ---------- bake invariants ----------
    int goff1[5], lds1o[5];              // preamble quads
    #pragma unroll
    for (int k = 0; k < 5; ++k) {
        const int q = tid + 512 * k;
        if (q < NQ1) {
            const int r = q >> 6, cc0 = (q & 63) << 2;
            int gi = min(max(by - 8 + r, 0), H - 1);
            const int gj = (bx - 8 + cc0 + W) % W;
            goff1[k] = gi * W + gj;
            lds1o[k] = r * LST + cc0;
        } else goff1[k] = -1;
    }

    int hgo[3], hlo[3];                  // halo import quads
    #pragma unroll
    for (int t = 0; t < 3; ++t) {
        const int q = tid + 512 * t;
        if (q < NHALO) {
            int r, cc0;
            if (q < 1024) { const int ri = q >> 6; r = (ri < 8) ? ri : 18 + ri; cc0 = (q & 63) << 2; }
            else { const int u = q - 1024; r = 8 + (u >> 2); const int qi = u & 3;
                   cc0 = (qi < 2) ? (qi << 2) : (248 + ((qi - 2) << 2)); }
            int gi = min(max(by - 8 + r, 0), H - 1);
            const int gj = (bx - 8 + cc0 + W) % W;
            hgo[t] = gi * W + gj;
            hlo[t] = r * LST + cc0;
        } else hgo[t] = -1;
    }

    // advection coeffs for own 6 h rows (wrapped gj -> halo cols evolve truly)
    float cuA[6][4], cvA[6][4];
    unsigned domm = 0;
    #pragma unroll
    for (int j = 0; j < 6; ++j) {
        #pragma unroll
        for (int t = 0; t < 4; ++t) { cuA[j][t] = 0.f; cvA[j][t] = 0.f; }
        const int gi = by - 8 + a + j;
        if ((unsigned)gi < H) {
            const float dxv  = REARTH * D2R * dlon * cosf(lat[gi] * D2R);
            const float rdx2 = 0.5f / dxv;
            const float ivy  = (gi == 0 || gi == H - 1) ? i1dy : i2dy;
            #pragma unroll
            for (int t = 0; t < 4; ++t) {
                const int off = gi * W + gj0 + t;
                const float mk = mask[off];
                cuA[j][t] = -DTS * mk * ub[off] * rdx2;
                cvA[j][t] = -DTS * mk * vb[off] * sgn * ivy;
            }
            domm |= 1u << j;
        }
    }

    // out rows n = 2+4rg+i, i = 0..3
    float m16A[4][4];
    int o3A[4];
    unsigned outm = 0, tilem = 0, ringm = 0;
    #pragma unroll
    for (int i = 0; i < 4; ++i) {
        const int n = 2 + 4 * rg + i;
        const int gi = by - 8 + n;
        o3A[i] = 0;
        #pragma unroll
        for (int t = 0; t < 4; ++t)
            m16A[i][t] = ((unsigned)gi < H) ? mask[gi * W + gj0 + t] * (1.f / 16.f) : 0.f;
        // writable rows: 2..31 (h-row validity caps at 32); in-domain only
        if (n <= 31 && (unsigned)gi < H) outm |= 1u << i;
        const bool inTile = (n >= 8 && n <= 25 && cq >= 2 && cq <= 61);
        if (inTile) {
            o3A[i] = gi * W + bx + c0 - 8;
            tilem |= 1u << i;
            if (n <= 15 || n >= 18 || cq <= 3 || cq >= 60) ringm |= 1u << i;
        }
    }
    const int wbase = (2 + 4 * rg) * LST + c0;           // LDS write base (row n0)
    const int rbase = 4 * rg * LST + c0;                 // LDS read base (row a-1)
    const int rtop  = (WR - 1) * LST + c0;               // clamp (bites only rg7)

    // neighbor flag pointers (8-neighborhood; x wraps, y clamps to self)
    const int* nbrF = myflag;
    if (tid < 8) {
        int dyn, dxn;
        if (tid < 3)      { dyn = -1; dxn = tid - 1; }
        else if (tid == 3){ dyn = 0;  dxn = -1; }
        else if (tid == 4){ dyn = 0;  dxn = 1; }
        else              { dyn = 1;  dxn = tid - 6; }
        const int ny = (int)blockIdx.y + dyn;
        const int nx = ((int)blockIdx.x + dxn + XC) % XC;
        if (ny >= 0 && ny < YC) nbrF = bflags + (ny * XC + nx) * FLAG_STRIDE;
    }

    // ---------- preamble: full window -> BOTH buffers ----------
    // (buf1's never-rewritten rows 0,1,32,33 must hold finite values; they
    //  feed only domm-zeroed h rows or outputs outside the validity window.)
    #pragma unroll
    for (int k = 0; k < 5; ++k)
        if (goff1[k] >= 0) {
            const float4 v = *(const float4*)(Tb + goff1[k]);
            *(float4*)(sT + lds1o[k])       = v;
            *(float4*)(sT + LSZ + lds1o[k]) = v;
        }
    __syncthreads();

    // ---------- one substep: read buf p, write buf p^1, ONE barrier ----------
    auto substep = [&](int p, bool finalOut, float* ring) {
        const float* cur = sT + p * LSZ;
        float* nxt = sT + (p ^ 1) * LSZ;
        float4 hA[6];
        float4 m1 = *(const float4*)(cur + rbase);
        float4 cc = *(const float4*)(cur + rbase + LST);
        #pragma unroll
        for (int j = 0; j < 6; ++j) {
            const float4 vD = *(const float4*)(cur + min(rbase + (j + 2) * LST, rtop));
            const float tl = dpp_up1(cc.w);    // 0 only at cq=0 -> col 0 (unconsumed)
            const float tr = dpp_dn1(cc.x);    // 0 only at cq=63 -> col 255
            const bool dj = (domm >> j) & 1;
            float4 o;
            o.x = (dj ? cc.x : 0.f) + cuA[j][0]*(cc.y - tl)   + cvA[j][0]*(vD.x - m1.x);
            o.y = (dj ? cc.y : 0.f) + cuA[j][1]*(cc.z - cc.x) + cvA[j][1]*(vD.y - m1.y);
            o.z = (dj ? cc.z : 0.f) + cuA[j][2]*(cc.w - cc.y) + cvA[j][2]*(vD.z - m1.z);
            o.w = (dj ? cc.w : 0.f) + cuA[j][3]*(tr   - cc.z) + cvA[j][3]*(vD.w - m1.w);
            float hl = dpp_up1(o.w);
            float hr = dpp_dn1(o.x);
            if (hlzb) hl = 0.f;
            if (hrzb) hr = 0.f;
            hA[j].x = hl  + 2.f * o.x + o.y;
            hA[j].y = o.x + 2.f * o.y + o.z;
            hA[j].z = o.y + 2.f * o.z + o.w;
            hA[j].w = o.z + 2.f * o.w + hr;
            m1 = cc; cc = vD;
        }
        // no mid-substep barrier: stage2 writes the OTHER buffer
        #pragma unroll
        for (int i = 0; i < 4; ++i) {
            const float4 hm = hA[i], hc = hA[i + 1], hp = hA[i + 2];
            float4 o;
            o.x = (hm.x + 2.f * hc.x + hp.x) * m16A[i][0];
            o.y = (hm.y + 2.f * hc.y + hp.y) * m16A[i][1];
            o.z = (hm.z + 2.f * hc.z + hp.z) * m16A[i][2];
            o.w = (hm.w + 2.f * hc.w + hp.w) * m16A[i][3];
            if (!finalOut) {
                if ((outm >> i) & 1)
                    *(float4*)(nxt + wbase + i * LST) = o;
                // clamp-replica patches (unique writers: edge rows suppressed above)
                if (topB && rg == 1 && i == 2) *(float4*)(nxt + 7  * LST + c0) = o; // row7  <- n=8
                if (botB && rg == 5 && i == 3) *(float4*)(nxt + 26 * LST + c0) = o; // row26 <- n=25
            } else if ((tilem >> i) & 1) {
                *(float4*)(outb + o3A[i]) = o;
            }
            if (ring && ((ringm >> i) & 1)) {
                float2 lo; lo.x = o.x; lo.y = o.y;
                float2 hi; hi.x = o.z; hi.y = o.w;
                stc8(ring + o3A[i], lo);
                stc8(ring + o3A[i] + 2, hi);
            }
        }
        __syncthreads();
    };

    // ---------- 5 groups x 4 substeps ----------
    // Parity: substeps read 0,1,0,1 -> group always ends with data in buf0,
    // and the halo import always lands in buf0.
    #pragma unroll 1
    for (int g = 0; g < NGROUPS; ++g) {
        if (g) {
            __syncthreads();   // drains ring stores (per-wave vmcnt0 before s_barrier)
            if (tid == 0)
                __hip_atomic_store(myflag, g, __ATOMIC_RELAXED, __HIP_MEMORY_SCOPE_AGENT);
            if (tid < 64) {    // wave 0, lanes 0..7 poll the 8 neighbors
                long long t0c = (long long)clock64();
                for (;;) {
                    const int v = (tid < 8)
                        ? __hip_atomic_load(nbrF, __ATOMIC_RELAXED, __HIP_MEMORY_SCOPE_AGENT)
                        : 0x7fffffff;
                    if (__all(v >= g)) break;
                    __builtin_amdgcn_s_sleep(1);
                    if ((long long)clock64() - t0c > 200000000LL) break;  // no-hang bailout
                }
            }
            __syncthreads();
            // halo import (depth 8) from ring(g-1): g-1 even -> outb, odd -> wsb
            const float* prev = ((g - 1) & 1) ? wsb : outb;
            #pragma unroll
            for (int t = 0; t < 3; ++t) {
                if (hgo[t] >= 0) {
                    const float2 lo = ldc8(prev + hgo[t]);
                    const float2 hi = ldc8(prev + hgo[t] + 2);
                    float4 v; v.x = lo.x; v.y = lo.y; v.z = hi.x; v.w = hi.y;
                    *(float4*)(sT + hlo[t]) = v;   // buf0 = current data buffer
                }
            }
            __syncthreads();
        }
        const bool lastG = (g == NGROUPS - 1);
        float* ringp = lastG ? nullptr : ((g & 1) ? wsb : outb);   // ring(g)
        substep(0, false, nullptr);
        substep(1, false, nullptr);
        substep(0, false, nullptr);
        substep(1, lastG, ringp);            // 4th substep: export ring / final tile
    }
}

extern "C" void kernel_launch(void* const* d_in, const int* in_sizes, int n_in,
                              void* d_out, int out_size, void* d_ws, size_t ws_size,
                              hipStream_t stream)
{
    const float* T    = (const float*)d_in[0];
    const float* ug   = (const float*)d_in[1];
    const float* vg   = (const float*)d_in[2];
    const float* lat  = (const float*)d_in[3];
    const float* lon  = (const float*)d_in[4];
    const float* mask = (const float*)d_in[5];
    float* out = (float*)d_out;

    int*   flags = (int*)d_ws;                        // 8 x 60 flags @ 128 B
    float* wsf   = (float*)((char*)d_ws + 65536);     // odd-group ring buffer

    hipMemsetAsync(d_ws, 0, 65536, stream);

    ocean_persist<<<dim3(XC, YC, NB), dim3(512), 0, stream>>>(
        T, ug, vg, lat, lon, mask, out, wsf, flags);
}

// Round 5
// 172.246 us; speedup vs baseline: 1.4398x; 1.0545x over previous
//
#include <hip/hip_runtime.h>

#define H 360
#define W 720
#define NB 8
#define XC 4
#define YC 8
#define TX 180
#define TY 45
#define BPB (XC*YC)             // 32 blocks per batch
#define DH 16                   // halo depth (rows AND cols)
#define WR 77                   // window rows = TY + 2*DH
#define NQ 53                   // col quads (window cols 212 = TX + 2*DH)
#define LST 216                 // LDS row stride floats (212 + 4 pad)
#define LSZ (WR*LST)
#define DTS 600.0f
#define REARTH 6371000.0f
#define D2R 0.017453292519943295f

#define NQ1 (WR*NQ)             // 4081 preamble quads
#define NHALO (32*NQ + 45*8)    // 2056 halo-import quads
#define FLAG_STRIDE 32          // 128 B per flag line

// Round 5: HALVE THE SYNC ROUNDS. R4's spin-traffic arithmetic shows each
// LLC sync round costs ~6 us (~25 us total in R2 = 35% of runtime). Round
// count = 20 / (DH-2)/2... depth was capped at 8 by the 256-col window at
// XC=3. XC=4 frees columns: DH=16 -> groups {7,7,6} -> 2 sync rounds.
// Also: launch_bounds 2nd arg is CUDA min-BLOCKS semantics on this
// toolchain (R3: (512,2)->128 VGPR cap -> spill; R4: (512,4)->64).
// (512,1) -> 256 VGPR cap, needed for the 11-row coefficient set.

// LLC-coherent 8B load/store (agent-scope relaxed atomic -> dwordx2 sc1)
static __device__ __forceinline__ float2 ldc8(const float* p) {
    unsigned long long u = __hip_atomic_load((const unsigned long long*)p,
                                             __ATOMIC_RELAXED, __HIP_MEMORY_SCOPE_AGENT);
    return __builtin_bit_cast(float2, u);
}
static __device__ __forceinline__ void stc8(float* p, float2 v) {
    __hip_atomic_store((unsigned long long*)p, __builtin_bit_cast(unsigned long long, v),
                       __ATOMIC_RELAXED, __HIP_MEMORY_SCOPE_AGENT);
}

// DPP wave-wide lane shifts on the VALU pipe (bound_ctrl=1: shifted-in lanes
// read 0 — lands only in window edge cols, the unconsumed degraded halo).
static __device__ __forceinline__ float dpp_up1(float x) {   // lane i <- lane i-1
    return __builtin_bit_cast(float, __builtin_amdgcn_update_dpp(
        0, __builtin_bit_cast(int, x), 0x138 /*wave_shr:1*/, 0xF, 0xF, true));
}
static __device__ __forceinline__ float dpp_dn1(float x) {   // lane i <- lane i+1
    return __builtin_bit_cast(float, __builtin_amdgcn_update_dpp(
        0, __builtin_bit_cast(int, x), 0x130 /*wave_shl:1*/, 0xF, 0xF, true));
}

__global__ __launch_bounds__(512, 1) void ocean_persist(
    const float* __restrict__ Tin, const float* __restrict__ ug,
    const float* __restrict__ vg, const float* __restrict__ lat,
    const float* __restrict__ lon, const float* __restrict__ mask,
    float* __restrict__ out, float* __restrict__ wsf, int* __restrict__ flags)
{
    // Double-buffered window (133 KB): substep reads buf p, writes buf p^1,
    // one barrier per substep. Import always lands in buf[cur] (= freshest).
    __shared__ float sT[2 * LSZ];

    const int tid = threadIdx.x;
    const int b  = blockIdx.z;
    const int bx = blockIdx.x * TX;
    const int by = blockIdx.y * TY;
    const int plane = H * W;

    const float dlat = lat[1] - lat[0];               // -0.5
    const float dy   = REARTH * D2R * fabsf(dlat);
    const float sgn  = (dlat > 0.f) ? 1.f : -1.f;
    const float dlon = lon[1] - lon[0];
    const float i2dy = 0.5f / dy, i1dy = 1.f / dy;

    const float* Tb = Tin + b * plane;
    const float* ub = ug  + b * plane;
    const float* vb = vg  + b * plane;
    float* outb = out + b * plane;
    float* wsb  = wsf + b * plane;

    int* bflags = flags + b * BPB * FLAG_STRIDE;
    int* myflag = bflags + (blockIdx.y * XC + blockIdx.x) * FLAG_STRIDE;

    // ---------- strip mapping: 8 waves x 9-row output pitch ----------
    const int cq = tid & 63;             // col quad; active cq < 53
    const int rg = tid >> 6;             // wave id 0..7
    const int c0 = (cq < NQ ? cq : 0) << 2;   // idle lanes clamp to col 0
    const int a  = 3 + 9 * rg;           // first h row; h rows a..a+10
    const int n0 = 4 + 9 * rg;           // first out row
    const int gj0 = (bx - DH + c0 + W) % W;
    const bool hlzb = (gj0 == 0);            // filter zero-pad left of gj=0
    const bool hrzb = (gj0 + 3 == W - 1);    // filter zero-pad right of gj=W-1

    // ---------- bake invariants ----------
    int goff1[8], lds1o[8];              // preamble quads
    #pragma unroll
    for (int k = 0; k < 8; ++k) {
        const int q = tid + 512 * k;
        if (q < NQ1) {
            const int r = q / NQ, cc0 = (q % NQ) << 2;
            const int gi = min(max(by - DH + r, 0), H - 1);
            const int gj = (bx - DH + cc0 + W) % W;
            goff1[k] = gi * W + gj;
            lds1o[k] = r * LST + cc0;
        } else goff1[k] = -1;
    }

    int hgo[5], hlo[5];                  // halo import quads
    #pragma unroll
    for (int t = 0; t < 5; ++t) {
        const int q = tid + 512 * t;
        if (q < NHALO) {
            int r, cc0;
            if (q < 32 * NQ) {           // row bands: r in {0..15, 61..76}
                const int ri = q / NQ; r = (ri < 16) ? ri : 45 + ri;
                cc0 = (q % NQ) << 2;
            } else {                     // col bands: rows 16..60, quads {0..3, 49..52}
                const int u = q - 32 * NQ; r = 16 + (u >> 3); const int qi = u & 7;
                cc0 = ((qi < 4) ? qi : (45 + qi)) << 2;
            }
            const int gi = min(max(by - DH + r, 0), H - 1);
            const int gj = (bx - DH + cc0 + W) % W;
            hgo[t] = gi * W + gj;
            hlo[t] = r * LST + cc0;
        } else hgo[t] = -1;
    }

    // advection coeffs for own 11 h rows (wrapped gj -> halo evolves truly)
    float cuA[11][4], cvA[11][4];
    unsigned domm = 0, topm = 0, botm = 0;
    #pragma unroll
    for (int j = 0; j < 11; ++j) {
        #pragma unroll
        for (int t = 0; t < 4; ++t) { cuA[j][t] = 0.f; cvA[j][t] = 0.f; }
        const int gi = by - DH + a + j;
        if ((unsigned)gi < H) {
            const float dxv  = REARTH * D2R * dlon * cosf(lat[gi] * D2R);
            const float rdx2 = 0.5f / dxv;
            const float ivy  = (gi == 0 || gi == H - 1) ? i1dy : i2dy;
            #pragma unroll
            for (int t = 0; t < 4; ++t) {
                const int off = gi * W + gj0 + t;
                const float mk = mask[off];
                cuA[j][t] = -DTS * mk * ub[off] * rdx2;
                cvA[j][t] = -DTS * mk * vb[off] * sgn * ivy;
            }
            domm |= 1u << j;
            if (gi == 0)     topm |= 1u << j;   // one-sided: row above := self
            if (gi == H - 1) botm |= 1u << j;   // one-sided: row below := self
        }
    }

    // out rows n = n0+i, i = 0..8; static band rows 4..72
    float m16A[9][4];
    unsigned outm = 0, tilem = 0, ringm = 0;
    #pragma unroll
    for (int i = 0; i < 9; ++i) {
        const int n = n0 + i;
        const int gi = by - DH + n;
        #pragma unroll
        for (int t = 0; t < 4; ++t)
            m16A[i][t] = ((unsigned)gi < H) ? mask[gi * W + gj0 + t] * (1.f / 16.f) : 0.f;
        if (n <= 72 && (unsigned)gi < H && cq < NQ) outm |= 1u << i;
        if (n >= 16 && n <= 60 && cq >= 4 && cq <= 48) {
            tilem |= 1u << i;
            const bool rowBand = (n <= 31) || (n >= 45);
            const bool colBand = (cq <= 7) || (cq >= 45);
            if (rowBand || colBand) ringm |= 1u << i;
        }
    }
    const int obase = (by - DH + n0) * W + bx - DH + c0;  // used only where masked valid
    const int wbase = n0 * LST + c0;
    const int rbase = (2 + 9 * rg) * LST + c0;            // first read row = a-1
    const int rtop  = (WR - 1) * LST + c0;                // read clamp (bites rg7)

    // neighbor flag pointers (8-neighborhood; x wraps, y clamps to self)
    const int* nbrF = myflag;
    if (tid < 8) {
        int dyn, dxn;
        if (tid < 3)      { dyn = -1; dxn = tid - 1; }
        else if (tid == 3){ dyn = 0;  dxn = -1; }
        else if (tid == 4){ dyn = 0;  dxn = 1; }
        else              { dyn = 1;  dxn = tid - 6; }
        const int ny = (int)blockIdx.y + dyn;
        const int nx = ((int)blockIdx.x + dxn + XC) % XC;
        if (ny >= 0 && ny < YC) nbrF = bflags + (ny * XC + nx) * FLAG_STRIDE;
    }

    // ---------- preamble: full window -> BOTH buffers ----------
    #pragma unroll
    for (int k = 0; k < 8; ++k)
        if (goff1[k] >= 0) {
            const float4 v = *(const float4*)(Tb + goff1[k]);
            *(float4*)(sT + lds1o[k])       = v;
            *(float4*)(sT + LSZ + lds1o[k]) = v;
        }
    __syncthreads();

    // ---------- one substep: read buf p, write buf p^1, ONE barrier ----------
    auto substep = [&](int p, bool finalOut, float* ring) {
        const float* cur = sT + p * LSZ;
        float* nxt = sT + (p ^ 1) * LSZ;
        float4 hA[11];
        float4 m1 = *(const float4*)(cur + rbase);
        float4 cc = *(const float4*)(cur + rbase + LST);
        #pragma unroll
        for (int j = 0; j < 11; ++j) {
            const float4 vD = *(const float4*)(cur + min(rbase + (j + 2) * LST, rtop));
            // domain-edge one-sided derivative via in-register replica
            const float4 m1e = ((topm >> j) & 1) ? cc : m1;
            const float4 vDe = ((botm >> j) & 1) ? cc : vD;
            const float tl = dpp_up1(cc.w);    // garbage only at window col 0
            const float tr = dpp_dn1(cc.x);    // garbage only at window col 211
            const bool dj = (domm >> j) & 1;
            float4 o;
            o.x = (dj ? cc.x : 0.f) + cuA[j][0]*(cc.y - tl)   + cvA[j][0]*(vDe.x - m1e.x);
            o.y = (dj ? cc.y : 0.f) + cuA[j][1]*(cc.z - cc.x) + cvA[j][1]*(vDe.y - m1e.y);
            o.z = (dj ? cc.z : 0.f) + cuA[j][2]*(cc.w - cc.y) + cvA[j][2]*(vDe.z - m1e.z);
            o.w = (dj ? cc.w : 0.f) + cuA[j][3]*(tr   - cc.z) + cvA[j][3]*(vDe.w - m1e.w);
            float hl = dpp_up1(o.w);
            float hr = dpp_dn1(o.x);
            if (hlzb) hl = 0.f;
            if (hrzb) hr = 0.f;
            hA[j].x = hl  + 2.f * o.x + o.y;
            hA[j].y = o.x + 2.f * o.y + o.z;
            hA[j].z = o.y + 2.f * o.z + o.w;
            hA[j].w = o.z + 2.f * o.w + hr;
            m1 = cc; cc = vD;
        }
        // stage2 writes the OTHER buffer: no mid-substep barrier
        #pragma unroll
        for (int i = 0; i < 9; ++i) {
            const float4 hm = hA[i], hc = hA[i + 1], hp = hA[i + 2];
            float4 o;
            o.x = (hm.x + 2.f * hc.x + hp.x) * m16A[i][0];
            o.y = (hm.y + 2.f * hc.y + hp.y) * m16A[i][1];
            o.z = (hm.z + 2.f * hc.z + hp.z) * m16A[i][2];
            o.w = (hm.w + 2.f * hc.w + hp.w) * m16A[i][3];
            if (!finalOut) {
                if ((outm >> i) & 1)
                    *(float4*)(nxt + wbase + i * LST) = o;
            } else if ((tilem >> i) & 1) {
                *(float4*)(outb + obase + i * W) = o;
            }
            if (ring && ((ringm >> i) & 1)) {
                float2 lo; lo.x = o.x; lo.y = o.y;
                float2 hi; hi.x = o.z; hi.y = o.w;
                stc8(ring + obase + i * W, lo);
                stc8(ring + obase + i * W + 2, hi);
            }
        }
        __syncthreads();
    };

    // ---------- 3 groups: {7,7,6} substeps, 2 sync rounds ----------
    int cur = 0;
    #pragma unroll 1
    for (int g = 0; g < 3; ++g) {
        if (g) {
            __syncthreads();   // drains ring stores (per-wave vmcnt0 before s_barrier)
            if (tid == 0)
                __hip_atomic_store(myflag, g, __ATOMIC_RELAXED, __HIP_MEMORY_SCOPE_AGENT);
            if (tid < 64) {    // wave 0, lanes 0..7 poll the 8 neighbors
                long long t0c = (long long)clock64();
                for (;;) {
                    const int v = (tid < 8)
                        ? __hip_atomic_load(nbrF, __ATOMIC_RELAXED, __HIP_MEMORY_SCOPE_AGENT)
                        : 0x7fffffff;
                    if (__all(v >= g)) break;
                    __builtin_amdgcn_s_sleep(1);
                    if ((long long)clock64() - t0c > 200000000LL) break;  // no-hang bailout
                }
            }
            __syncthreads();
            // halo import from ring(g-1): g=1 <- outb, g=2 <- wsb; into buf[cur]
            const float* prev = (g == 1) ? outb : wsb;
            float* dst = sT + cur * LSZ;
            #pragma unroll
            for (int t = 0; t < 5; ++t) {
                if (hgo[t] >= 0) {
                    const float2 lo = ldc8(prev + hgo[t]);
                    const float2 hi = ldc8(prev + hgo[t] + 2);
                    float4 v; v.x = lo.x; v.y = lo.y; v.z = hi.x; v.w = hi.y;
                    *(float4*)(dst + hlo[t]) = v;
                }
            }
            __syncthreads();
        }
        const int S = (g == 2) ? 6 : 7;
        float* ringp = (g == 0) ? outb : ((g == 1) ? wsb : nullptr);
        #pragma unroll 1
        for (int s = 0; s < S; ++s) {
            const bool lastS = (s == S - 1);
            substep(cur, (g == 2) && lastS, (g < 2 && lastS) ? ringp : nullptr);
            cur ^= 1;
        }
    }
}

extern "C" void kernel_launch(void* const* d_in, const int* in_sizes, int n_in,
                              void* d_out, int out_size, void* d_ws, size_t ws_size,
                              hipStream_t stream)
{
    const float* T    = (const float*)d_in[0];
    const float* ug   = (const float*)d_in[1];
    const float* vg   = (const float*)d_in[2];
    const float* lat  = (const float*)d_in[3];
    const float* lon  = (const float*)d_in[4];
    const float* mask = (const float*)d_in[5];
    float* out = (float*)d_out;

    int*   flags = (int*)d_ws;                        // 8 x 32 flags @ 128 B
    float* wsf   = (float*)((char*)d_ws + 65536);     // odd-ring buffer (g=1)

    hipMemsetAsync(d_ws, 0, 65536, stream);

    ocean_persist<<<dim3(XC, YC, NB), dim3(512), 0, stream>>>(
        T, ug, vg, lat, lon, mask, out, wsf, flags);
}

// Round 6
// 140.498 us; speedup vs baseline: 1.7651x; 1.2260x over previous
//
#include <hip/hip_runtime.h>

#define H 360
#define W 720
#define NB 8
#define XC 3
#define YC 10
#define TX 240
#define TY 36
#define BPB (XC*YC)             // 30 blocks per batch
#define WR 52                   // window rows: gi = by-8+r, r in 0..51
#define LST 260                 // LDS row stride (floats): 256 cols + 4 pad
#define LSZ (WR*LST)            // one window buffer (floats)
#define DTS 600.0f
#define REARTH 6371000.0f
#define D2R 0.017453292519943295f

#define NQ1 (WR*64)             // 3328 preamble quads
#define NHALO 1168              // rows{0..7,44..51}x64 + rows 8..43 x quads{0,1,62,63}
#define NGROUPS 5               // 5 groups x 4 substeps = 20 steps
#define FLAG_STRIDE 32          // 128 B per flag line

// Round 6: R2 geometry (proven best, 67us) with the SPILL REMOVED.
// Cap model fit to R0-R5: VGPR cap = min(128, 512/(blocks*waves/4)), 2nd
// launch_bounds arg = CUDA min-BLOCKS. R2's (1024,4) -> 64 VGPR vs ~100
// needed -> per-substep scratch reloads. Fix: (1024,1) -> 128 cap, and
// shrink demand: rolling 3-deep h pipeline (was hA[5]), m16 -> 12-bit
// bitmask (mask/16 = bit*0.0625 exactly), in-register topm/botm edge
// replica (drops LDS patch writes; proven in R5).

// LLC-coherent 8B load/store (agent-scope relaxed atomic -> dwordx2 sc1)
static __device__ __forceinline__ float2 ldc8(const float* p) {
    unsigned long long u = __hip_atomic_load((const unsigned long long*)p,
                                             __ATOMIC_RELAXED, __HIP_MEMORY_SCOPE_AGENT);
    return __builtin_bit_cast(float2, u);
}
static __device__ __forceinline__ void stc8(float* p, float2 v) {
    __hip_atomic_store((unsigned long long*)p, __builtin_bit_cast(unsigned long long, v),
                       __ATOMIC_RELAXED, __HIP_MEMORY_SCOPE_AGENT);
}

// DPP wave-wide lane shifts on the VALU pipe (bound_ctrl=1: shifted-in lanes
// read 0 — lands only in window cols 0/255, the unconsumed degraded halo).
static __device__ __forceinline__ float dpp_up1(float x) {   // lane i <- lane i-1
    return __builtin_bit_cast(float, __builtin_amdgcn_update_dpp(
        0, __builtin_bit_cast(int, x), 0x138 /*wave_shr:1*/, 0xF, 0xF, true));
}
static __device__ __forceinline__ float dpp_dn1(float x) {   // lane i <- lane i+1
    return __builtin_bit_cast(float, __builtin_amdgcn_update_dpp(
        0, __builtin_bit_cast(int, x), 0x130 /*wave_shl:1*/, 0xF, 0xF, true));
}

__global__ __launch_bounds__(1024, 1) void ocean_persist(
    const float* __restrict__ Tin, const float* __restrict__ ug,
    const float* __restrict__ vg, const float* __restrict__ lat,
    const float* __restrict__ lon, const float* __restrict__ mask,
    float* __restrict__ out, float* __restrict__ wsf, int* __restrict__ flags)
{
    // Double-buffered window: substep reads buf p, writes buf p^1 ->
    // one barrier per substep. 108 KB LDS, 1 block/CU (grid caps residency).
    __shared__ float sT[2 * LSZ];

    const int tid = threadIdx.x;
    const int b  = blockIdx.z;
    const int bx = blockIdx.x * TX;
    const int by = blockIdx.y * TY;
    const int plane = H * W;

    const float dlat = lat[1] - lat[0];               // -0.5
    const float dy   = REARTH * D2R * fabsf(dlat);
    const float sgn  = (dlat > 0.f) ? 1.f : -1.f;
    const float dlon = lon[1] - lon[0];
    const float i2dy = 0.5f / dy, i1dy = 1.f / dy;

    const float* Tb = Tin + b * plane;
    const float* ub = ug  + b * plane;
    const float* vb = vg  + b * plane;
    float* outb = out + b * plane;
    float* wsb  = wsf + b * plane;

    int* bflags = flags + b * BPB * FLAG_STRIDE;
    int* myflag = bflags + (blockIdx.y * XC + blockIdx.x) * FLAG_STRIDE;

    // ---------- strip mapping: 16 waves x 3-row output pitch ----------
    const int cq = tid & 63;             // col quad 0..63 (window cols 0..255)
    const int rg = tid >> 6;             // row group 0..15 (== wave id)
    const int c0 = cq << 2;
    const int a  = 1 + 3 * rg;           // first h row; h rows a..a+4 (j<5)
    const int gj0 = (bx - 8 + c0 + W) % W;
    const bool hlzb = (gj0 == 0);            // filter zero-pad left of gj=0
    const bool hrzb = (gj0 + 3 == W - 1);    // filter zero-pad right of gj=W-1

    // ---------- bake invariants ----------
    int goff1[4], lds1o[4];              // preamble quads (1024-thread stride)
    #pragma unroll
    for (int k = 0; k < 4; ++k) {
        const int q = tid + 1024 * k;
        if (q < NQ1) {
            const int r = q >> 6, cc0 = (q & 63) << 2;
            const int gi = min(max(by - 8 + r, 0), H - 1);
            const int gj = (bx - 8 + cc0 + W) % W;
            goff1[k] = gi * W + gj;
            lds1o[k] = r * LST + cc0;
        } else goff1[k] = -1;
    }

    int hgo[2], hlo[2];                  // halo import quads (2/thread)
    #pragma unroll
    for (int t = 0; t < 2; ++t) {
        const int q = tid + 1024 * t;
        if (q < NHALO) {
            int r, cc0;
            if (q < 1024) { const int ri = q >> 6; r = (ri < 8) ? ri : 36 + ri; cc0 = (q & 63) << 2; }
            else { const int u = q - 1024; r = 8 + (u >> 2); const int qi = u & 3;
                   cc0 = (qi < 2) ? (qi << 2) : (248 + ((qi - 2) << 2)); }
            const int gi = min(max(by - 8 + r, 0), H - 1);
            const int gj = (bx - 8 + cc0 + W) % W;
            hgo[t] = gi * W + gj;
            hlo[t] = r * LST + cc0;
        } else hgo[t] = -1;
    }

    // advection coeffs for own 5 h rows (wrapped gj -> halo cols evolve truly)
    float cuA[5][4], cvA[5][4];
    unsigned domm = 0, topm = 0, botm = 0;
    #pragma unroll
    for (int j = 0; j < 5; ++j) {
        #pragma unroll
        for (int t = 0; t < 4; ++t) { cuA[j][t] = 0.f; cvA[j][t] = 0.f; }
        const int gi = by - 8 + a + j;
        if ((unsigned)gi < H) {
            const float dxv  = REARTH * D2R * dlon * cosf(lat[gi] * D2R);
            const float rdx2 = 0.5f / dxv;
            const float ivy  = (gi == 0 || gi == H - 1) ? i1dy : i2dy;
            #pragma unroll
            for (int t = 0; t < 4; ++t) {
                const int off = gi * W + gj0 + t;
                const float mk = mask[off];
                cuA[j][t] = -DTS * mk * ub[off] * rdx2;
                cvA[j][t] = -DTS * mk * vb[off] * sgn * ivy;
            }
            domm |= 1u << j;
            if (gi == 0)     topm |= 1u << j;   // one-sided: row above := self
            if (gi == H - 1) botm |= 1u << j;   // one-sided: row below := self
        }
    }

    // out rows n = 2+3rg+i, i = 0..2; m16 as 12-bit mask (mask/16 = bit*0.0625)
    unsigned mb = 0, outm = 0, tilem = 0, ringm = 0;
    int o3A[3];
    #pragma unroll
    for (int i = 0; i < 3; ++i) {
        const int n = 2 + 3 * rg + i;
        const int gi = by - 8 + n;
        o3A[i] = 0;
        #pragma unroll
        for (int t = 0; t < 4; ++t)
            if ((unsigned)gi < H && mask[gi * W + gj0 + t] != 0.f) mb |= 1u << (4 * i + t);
        if ((unsigned)gi < H) outm |= 1u << i;    // write sT (in-domain rows only)
        const bool inTile = (n >= 8 && n <= 43 && cq >= 2 && cq <= 61);
        if (inTile) {
            o3A[i] = gi * W + bx + c0 - 8;
            tilem |= 1u << i;
            if (n <= 15 || n >= 36 || cq <= 3 || cq >= 60) ringm |= 1u << i;
        }
    }
    const int rbase = 3 * rg * LST + c0;           // LDS read base (row a-1)
    const int wbase = (2 + 3 * rg) * LST + c0;     // LDS write base (row n0)

    // neighbor flag pointers (8-neighborhood; x wraps, y clamps to self)
    const int* nbrF = myflag;
    if (tid < 8) {
        int dyn, dxn;
        if (tid < 3)      { dyn = -1; dxn = tid - 1; }
        else if (tid == 3){ dyn = 0;  dxn = -1; }
        else if (tid == 4){ dyn = 0;  dxn = 1; }
        else              { dyn = 1;  dxn = tid - 6; }
        const int ny = (int)blockIdx.y + dyn;
        const int nx = ((int)blockIdx.x + dxn + XC) % XC;
        if (ny >= 0 && ny < YC) nbrF = bflags + (ny * XC + nx) * FLAG_STRIDE;
    }

    // ---------- preamble: full window -> BOTH buffers ----------
    // (buf1's never-rewritten rows 0,1,50,51 hold finite preamble values;
    //  they feed only domm-zeroed h rows / replica-overridden derivatives.)
    #pragma unroll
    for (int k = 0; k < 4; ++k)
        if (goff1[k] >= 0) {
            const float4 v = *(const float4*)(Tb + goff1[k]);
            *(float4*)(sT + lds1o[k])       = v;
            *(float4*)(sT + LSZ + lds1o[k]) = v;
        }
    __syncthreads();

    // ---------- one substep: rolling 3-deep h pipeline, ONE barrier ----------
    auto substep = [&](int p, bool finalOut, float* ring) {
        const float* cur = sT + p * LSZ;
        float* nxt = sT + (p ^ 1) * LSZ;
        float4 m1 = *(const float4*)(cur + rbase);             // row a-1
        float4 cc = *(const float4*)(cur + rbase + LST);       // row a
        float4 h0, h1;
        #pragma unroll
        for (int j = 0; j < 5; ++j) {
            const float4 vD = *(const float4*)(cur + rbase + (j + 2) * LST);
            // domain-edge one-sided derivative via in-register replica
            const float4 m1e = ((topm >> j) & 1) ? cc : m1;
            const float4 vDe = ((botm >> j) & 1) ? cc : vD;
            const float tl = dpp_up1(cc.w);    // 0 only at cq=0 -> col 0 (unconsumed)
            const float tr = dpp_dn1(cc.x);    // 0 only at cq=63 -> col 255
            const bool dj = (domm >> j) & 1;
            float4 o;
            o.x = (dj ? cc.x : 0.f) + cuA[j][0]*(cc.y - tl)   + cvA[j][0]*(vDe.x - m1e.x);
            o.y = (dj ? cc.y : 0.f) + cuA[j][1]*(cc.z - cc.x) + cvA[j][1]*(vDe.y - m1e.y);
            o.z = (dj ? cc.z : 0.f) + cuA[j][2]*(cc.w - cc.y) + cvA[j][2]*(vDe.z - m1e.z);
            o.w = (dj ? cc.w : 0.f) + cuA[j][3]*(tr   - cc.z) + cvA[j][3]*(vDe.w - m1e.w);
            float hl = dpp_up1(o.w);
            float hr = dpp_dn1(o.x);
            if (hlzb) hl = 0.f;
            if (hrzb) hr = 0.f;
            float4 hn;
            hn.x = hl  + 2.f * o.x + o.y;
            hn.y = o.x + 2.f * o.y + o.z;
            hn.z = o.y + 2.f * o.z + o.w;
            hn.w = o.z + 2.f * o.w + hr;
            if (j >= 2) {
                const int i = j - 2;                // out row n0+i
                float4 ov;
                const float sx = h0.x + 2.f * h1.x + hn.x;
                const float sy = h0.y + 2.f * h1.y + hn.y;
                const float sz = h0.z + 2.f * h1.z + hn.z;
                const float sw = h0.w + 2.f * h1.w + hn.w;
                ov.x = ((mb >> (4 * i + 0)) & 1) ? sx * 0.0625f : 0.f;
                ov.y = ((mb >> (4 * i + 1)) & 1) ? sy * 0.0625f : 0.f;
                ov.z = ((mb >> (4 * i + 2)) & 1) ? sz * 0.0625f : 0.f;
                ov.w = ((mb >> (4 * i + 3)) & 1) ? sw * 0.0625f : 0.f;
                if (!finalOut) {
                    if ((outm >> i) & 1)
                        *(float4*)(nxt + wbase + i * LST) = ov;
                } else if ((tilem >> i) & 1) {
                    *(float4*)(outb + o3A[i]) = ov;
                }
                if (ring && ((ringm >> i) & 1)) {
                    float2 lo; lo.x = ov.x; lo.y = ov.y;
                    float2 hi; hi.x = ov.z; hi.y = ov.w;
                    stc8(ring + o3A[i], lo);
                    stc8(ring + o3A[i] + 2, hi);
                }
            }
            h0 = h1; h1 = hn;
            m1 = cc; cc = vD;
        }
        __syncthreads();
    };

    // ---------- 5 groups x 4 substeps ----------
    // Parity: substeps read 0,1,0,1 -> group always ends with data in buf0,
    // and the halo import always lands in buf0.
    #pragma unroll 1
    for (int g = 0; g < NGROUPS; ++g) {
        if (g) {
            __syncthreads();   // drains ring stores (per-wave vmcnt0 before s_barrier)
            if (tid == 0)
                __hip_atomic_store(myflag, g, __ATOMIC_RELAXED, __HIP_MEMORY_SCOPE_AGENT);
            if (tid < 64) {    // wave 0, lanes 0..7 poll the 8 neighbors
                long long t0c = (long long)clock64();
                for (;;) {
                    const int v = (tid < 8)
                        ? __hip_atomic_load(nbrF, __ATOMIC_RELAXED, __HIP_MEMORY_SCOPE_AGENT)
                        : 0x7fffffff;
                    if (__all(v >= g)) break;
                    __builtin_amdgcn_s_sleep(1);
                    if ((long long)clock64() - t0c > 200000000LL) break;  // no-hang bailout
                }
            }
            __syncthreads();
            // halo import (depth 8) from ring(g-1): g-1 even -> outb, odd -> wsb
            const float* prev = ((g - 1) & 1) ? wsb : outb;
            #pragma unroll
            for (int t = 0; t < 2; ++t) {
                if (hgo[t] >= 0) {
                    const float2 lo = ldc8(prev + hgo[t]);
                    const float2 hi = ldc8(prev + hgo[t] + 2);
                    float4 v; v.x = lo.x; v.y = lo.y; v.z = hi.x; v.w = hi.y;
                    *(float4*)(sT + hlo[t]) = v;   // buf0 = current data buffer
                }
            }
            __syncthreads();
        }
        const bool lastG = (g == NGROUPS - 1);
        float* ringp = lastG ? nullptr : ((g & 1) ? wsb : outb);   // ring(g)
        substep(0, false, nullptr);
        substep(1, false, nullptr);
        substep(0, false, nullptr);
        substep(1, lastG, ringp);            // 4th substep: export ring / final tile
    }
}

extern "C" void kernel_launch(void* const* d_in, const int* in_sizes, int n_in,
                              void* d_out, int out_size, void* d_ws, size_t ws_size,
                              hipStream_t stream)
{
    const float* T    = (const float*)d_in[0];
    const float* ug   = (const float*)d_in[1];
    const float* vg   = (const float*)d_in[2];
    const float* lat  = (const float*)d_in[3];
    const float* lon  = (const float*)d_in[4];
    const float* mask = (const float*)d_in[5];
    float* out = (float*)d_out;

    int*   flags = (int*)d_ws;                        // 8 x 30 flags @ 128 B
    float* wsf   = (float*)((char*)d_ws + 65536);     // odd-group ring buffer

    hipMemsetAsync(d_ws, 0, 65536, stream);

    ocean_persist<<<dim3(XC, YC, NB), dim3(1024), 0, stream>>>(
        T, ug, vg, lat, lon, mask, out, wsf, flags);
}

// Round 7
// 140.477 us; speedup vs baseline: 1.7654x; 1.0001x over previous
//
#include <hip/hip_runtime.h>

#define H 360
#define W 720
#define NB 8
#define XC 3
#define YC 10
#define TX 240
#define TY 36
#define BPB (XC*YC)             // 30 blocks per batch
#define WR 52                   // window rows: gi = by-8+r, r in 0..51
#define LST 260                 // LDS row stride (floats): 256 cols + 4 pad
#define LSZ (WR*LST)            // one window buffer (floats)
#define DTS 600.0f
#define REARTH 6371000.0f
#define D2R 0.017453292519943295f

#define NQ1 (WR*64)             // 3328 preamble quads
#define NHALO 1168              // rows{0..7,44..51}x64 + rows 8..43 x quads{0,1,62,63}
#define NGROUPS 5               // 5 groups x 4 substeps = 20 steps
#define FLAG_STRIDE 32          // 128 B per flag line

// Round 7: INTERIOR FAST PATH. Of ~42 VALU ops/j in the inner loop, ~14 are
// edge-handling selects (dj/topm/botm/hlzb/hrzb) that are dead for all waves
// except y-edge rows (blocks y=0,9) and the longitude wrap (blockIdx.x==0
// only: bx=0 window spans gj=0 and gj=719; x=1,2 never). Wave-uniform
// fast/slow split -> no divergence cost. Also revert to R2's two-stage
// hA[5] staging (reads batched before writes): R6's rolling interleave
// raised SQ_LDS_BANK_CONFLICT 1.03M -> 5.29M (~9% of runtime).

// LLC-coherent 8B load/store (agent-scope relaxed atomic -> dwordx2 sc1)
static __device__ __forceinline__ float2 ldc8(const float* p) {
    unsigned long long u = __hip_atomic_load((const unsigned long long*)p,
                                             __ATOMIC_RELAXED, __HIP_MEMORY_SCOPE_AGENT);
    return __builtin_bit_cast(float2, u);
}
static __device__ __forceinline__ void stc8(float* p, float2 v) {
    __hip_atomic_store((unsigned long long*)p, __builtin_bit_cast(unsigned long long, v),
                       __ATOMIC_RELAXED, __HIP_MEMORY_SCOPE_AGENT);
}

// DPP wave-wide lane shifts on the VALU pipe (bound_ctrl=1: shifted-in lanes
// read 0 — lands only in window cols 0/255, the unconsumed degraded halo).
static __device__ __forceinline__ float dpp_up1(float x) {   // lane i <- lane i-1
    return __builtin_bit_cast(float, __builtin_amdgcn_update_dpp(
        0, __builtin_bit_cast(int, x), 0x138 /*wave_shr:1*/, 0xF, 0xF, true));
}
static __device__ __forceinline__ float dpp_dn1(float x) {   // lane i <- lane i+1
    return __builtin_bit_cast(float, __builtin_amdgcn_update_dpp(
        0, __builtin_bit_cast(int, x), 0x130 /*wave_shl:1*/, 0xF, 0xF, true));
}

__global__ __launch_bounds__(1024, 1) void ocean_persist(
    const float* __restrict__ Tin, const float* __restrict__ ug,
    const float* __restrict__ vg, const float* __restrict__ lat,
    const float* __restrict__ lon, const float* __restrict__ mask,
    float* __restrict__ out, float* __restrict__ wsf, int* __restrict__ flags)
{
    // Double-buffered window: substep reads buf p, writes buf p^1 ->
    // one barrier per substep. 108 KB LDS, 1 block/CU (grid caps residency).
    __shared__ float sT[2 * LSZ];

    const int tid = threadIdx.x;
    const int b  = blockIdx.z;
    const int bx = blockIdx.x * TX;
    const int by = blockIdx.y * TY;
    const int plane = H * W;

    const float dlat = lat[1] - lat[0];               // -0.5
    const float dy   = REARTH * D2R * fabsf(dlat);
    const float sgn  = (dlat > 0.f) ? 1.f : -1.f;
    const float dlon = lon[1] - lon[0];
    const float i2dy = 0.5f / dy, i1dy = 1.f / dy;

    const float* Tb = Tin + b * plane;
    const float* ub = ug  + b * plane;
    const float* vb = vg  + b * plane;
    float* outb = out + b * plane;
    float* wsb  = wsf + b * plane;

    int* bflags = flags + b * BPB * FLAG_STRIDE;
    int* myflag = bflags + (blockIdx.y * XC + blockIdx.x) * FLAG_STRIDE;

    // ---------- strip mapping: 16 waves x 3-row output pitch ----------
    const int cq = tid & 63;             // col quad 0..63 (window cols 0..255)
    const int rg = tid >> 6;             // row group 0..15 (== wave id)
    const int c0 = cq << 2;
    const int a  = 1 + 3 * rg;           // first h row; h rows a..a+4 (j<5)
    const int gj0 = (bx - 8 + c0 + W) % W;
    const bool hlzb = (gj0 == 0);            // filter zero-pad left of gj=0
    const bool hrzb = (gj0 + 3 == W - 1);    // filter zero-pad right of gj=W-1

    // ---------- bake invariants ----------
    int goff1[4], lds1o[4];              // preamble quads (1024-thread stride)
    #pragma unroll
    for (int k = 0; k < 4; ++k) {
        const int q = tid + 1024 * k;
        if (q < NQ1) {
            const int r = q >> 6, cc0 = (q & 63) << 2;
            const int gi = min(max(by - 8 + r, 0), H - 1);
            const int gj = (bx - 8 + cc0 + W) % W;
            goff1[k] = gi * W + gj;
            lds1o[k] = r * LST + cc0;
        } else goff1[k] = -1;
    }

    int hgo[2], hlo[2];                  // halo import quads (2/thread)
    #pragma unroll
    for (int t = 0; t < 2; ++t) {
        const int q = tid + 1024 * t;
        if (q < NHALO) {
            int r, cc0;
            if (q < 1024) { const int ri = q >> 6; r = (ri < 8) ? ri : 36 + ri; cc0 = (q & 63) << 2; }
            else { const int u = q - 1024; r = 8 + (u >> 2); const int qi = u & 3;
                   cc0 = (qi < 2) ? (qi << 2) : (248 + ((qi - 2) << 2)); }
            const int gi = min(max(by - 8 + r, 0), H - 1);
            const int gj = (bx - 8 + cc0 + W) % W;
            hgo[t] = gi * W + gj;
            hlo[t] = r * LST + cc0;
        } else hgo[t] = -1;
    }

    // advection coeffs for own 5 h rows (wrapped gj -> halo cols evolve truly)
    float cuA[5][4], cvA[5][4];
    unsigned domm = 0, topm = 0, botm = 0;
    #pragma unroll
    for (int j = 0; j < 5; ++j) {
        #pragma unroll
        for (int t = 0; t < 4; ++t) { cuA[j][t] = 0.f; cvA[j][t] = 0.f; }
        const int gi = by - 8 + a + j;
        if ((unsigned)gi < H) {
            const float dxv  = REARTH * D2R * dlon * cosf(lat[gi] * D2R);
            const float rdx2 = 0.5f / dxv;
            const float ivy  = (gi == 0 || gi == H - 1) ? i1dy : i2dy;
            #pragma unroll
            for (int t = 0; t < 4; ++t) {
                const int off = gi * W + gj0 + t;
                const float mk = mask[off];
                cuA[j][t] = -DTS * mk * ub[off] * rdx2;
                cvA[j][t] = -DTS * mk * vb[off] * sgn * ivy;
            }
            domm |= 1u << j;
            if (gi == 0)     topm |= 1u << j;   // one-sided: row above := self
            if (gi == H - 1) botm |= 1u << j;   // one-sided: row below := self
        }
    }
    // wave-uniform fast-path predicate (all conditions wave-uniform or __any)
    const bool fastW = (domm == 0x1fu) && !topm && !botm && !__any(hlzb || hrzb);

    // out rows n = 2+3rg+i, i = 0..2; m16 as 12-bit mask (mask/16 = bit*0.0625)
    unsigned mb = 0, outm = 0, tilem = 0, ringm = 0;
    int o3A[3];
    #pragma unroll
    for (int i = 0; i < 3; ++i) {
        const int n = 2 + 3 * rg + i;
        const int gi = by - 8 + n;
        o3A[i] = 0;
        #pragma unroll
        for (int t = 0; t < 4; ++t)
            if ((unsigned)gi < H && mask[gi * W + gj0 + t] != 0.f) mb |= 1u << (4 * i + t);
        if ((unsigned)gi < H) outm |= 1u << i;    // write sT (in-domain rows only)
        const bool inTile = (n >= 8 && n <= 43 && cq >= 2 && cq <= 61);
        if (inTile) {
            o3A[i] = gi * W + bx + c0 - 8;
            tilem |= 1u << i;
            if (n <= 15 || n >= 36 || cq <= 3 || cq >= 60) ringm |= 1u << i;
        }
    }
    const int rbase = 3 * rg * LST + c0;           // LDS read base (row a-1)
    const int wbase = (2 + 3 * rg) * LST + c0;     // LDS write base (row n0)

    // neighbor flag pointers (8-neighborhood; x wraps, y clamps to self)
    const int* nbrF = myflag;
    if (tid < 8) {
        int dyn, dxn;
        if (tid < 3)      { dyn = -1; dxn = tid - 1; }
        else if (tid == 3){ dyn = 0;  dxn = -1; }
        else if (tid == 4){ dyn = 0;  dxn = 1; }
        else              { dyn = 1;  dxn = tid - 6; }
        const int ny = (int)blockIdx.y + dyn;
        const int nx = ((int)blockIdx.x + dxn + XC) % XC;
        if (ny >= 0 && ny < YC) nbrF = bflags + (ny * XC + nx) * FLAG_STRIDE;
    }

    // ---------- preamble: full window -> BOTH buffers ----------
    // (buf1's never-rewritten rows 0,1,50,51 hold finite preamble values;
    //  they feed only domm-zeroed h rows / replica-overridden derivatives.)
    #pragma unroll
    for (int k = 0; k < 4; ++k)
        if (goff1[k] >= 0) {
            const float4 v = *(const float4*)(Tb + goff1[k]);
            *(float4*)(sT + lds1o[k])       = v;
            *(float4*)(sT + LSZ + lds1o[k]) = v;
        }
    __syncthreads();

    // ---------- one substep: two-stage hA[5], ONE barrier ----------
    auto substep = [&](int p, bool finalOut, float* ring) {
        const float* cur = sT + p * LSZ;
        float* nxt = sT + (p ^ 1) * LSZ;
        float4 hA[5];
        float4 m1 = *(const float4*)(cur + rbase);             // row a-1
        float4 cc = *(const float4*)(cur + rbase + LST);       // row a
        if (fastW) {
            // interior wave: no domain/edge/wrap selects (-14 VALU per j)
            #pragma unroll
            for (int j = 0; j < 5; ++j) {
                const float4 vD = *(const float4*)(cur + rbase + (j + 2) * LST);
                const float tl = dpp_up1(cc.w);
                const float tr = dpp_dn1(cc.x);
                float4 o;
                o.x = cc.x + cuA[j][0]*(cc.y - tl)   + cvA[j][0]*(vD.x - m1.x);
                o.y = cc.y + cuA[j][1]*(cc.z - cc.x) + cvA[j][1]*(vD.y - m1.y);
                o.z = cc.z + cuA[j][2]*(cc.w - cc.y) + cvA[j][2]*(vD.z - m1.z);
                o.w = cc.w + cuA[j][3]*(tr   - cc.z) + cvA[j][3]*(vD.w - m1.w);
                const float hl = dpp_up1(o.w);
                const float hr = dpp_dn1(o.x);
                hA[j].x = hl  + 2.f * o.x + o.y;
                hA[j].y = o.x + 2.f * o.y + o.z;
                hA[j].z = o.y + 2.f * o.z + o.w;
                hA[j].w = o.z + 2.f * o.w + hr;
                m1 = cc; cc = vD;
            }
        } else {
            // general wave: domain-edge replicas + wrap zero-pads (R6 logic)
            #pragma unroll
            for (int j = 0; j < 5; ++j) {
                const float4 vD = *(const float4*)(cur + rbase + (j + 2) * LST);
                const float4 m1e = ((topm >> j) & 1) ? cc : m1;
                const float4 vDe = ((botm >> j) & 1) ? cc : vD;
                const float tl = dpp_up1(cc.w);
                const float tr = dpp_dn1(cc.x);
                const bool dj = (domm >> j) & 1;
                float4 o;
                o.x = (dj ? cc.x : 0.f) + cuA[j][0]*(cc.y - tl)   + cvA[j][0]*(vDe.x - m1e.x);
                o.y = (dj ? cc.y : 0.f) + cuA[j][1]*(cc.z - cc.x) + cvA[j][1]*(vDe.y - m1e.y);
                o.z = (dj ? cc.z : 0.f) + cuA[j][2]*(cc.w - cc.y) + cvA[j][2]*(vDe.z - m1e.z);
                o.w = (dj ? cc.w : 0.f) + cuA[j][3]*(tr   - cc.z) + cvA[j][3]*(vDe.w - m1e.w);
                float hl = dpp_up1(o.w);
                float hr = dpp_dn1(o.x);
                if (hlzb) hl = 0.f;
                if (hrzb) hr = 0.f;
                hA[j].x = hl  + 2.f * o.x + o.y;
                hA[j].y = o.x + 2.f * o.y + o.z;
                hA[j].z = o.y + 2.f * o.z + o.w;
                hA[j].w = o.z + 2.f * o.w + hr;
                m1 = cc; cc = vD;
            }
        }
        // stage 2: batched writes after all reads (R2's low-conflict pattern)
        #pragma unroll
        for (int i = 0; i < 3; ++i) {
            const float4 hm = hA[i], hc = hA[i + 1], hp = hA[i + 2];
            float4 ov;
            const float sx = hm.x + 2.f * hc.x + hp.x;
            const float sy = hm.y + 2.f * hc.y + hp.y;
            const float sz = hm.z + 2.f * hc.z + hp.z;
            const float sw = hm.w + 2.f * hc.w + hp.w;
            ov.x = ((mb >> (4 * i + 0)) & 1) ? sx * 0.0625f : 0.f;
            ov.y = ((mb >> (4 * i + 1)) & 1) ? sy * 0.0625f : 0.f;
            ov.z = ((mb >> (4 * i + 2)) & 1) ? sz * 0.0625f : 0.f;
            ov.w = ((mb >> (4 * i + 3)) & 1) ? sw * 0.0625f : 0.f;
            if (!finalOut) {
                if ((outm >> i) & 1)
                    *(float4*)(nxt + wbase + i * LST) = ov;
            } else if ((tilem >> i) & 1) {
                *(float4*)(outb + o3A[i]) = ov;
            }
            if (ring && ((ringm >> i) & 1)) {
                float2 lo; lo.x = ov.x; lo.y = ov.y;
                float2 hi; hi.x = ov.z; hi.y = ov.w;
                stc8(ring + o3A[i], lo);
                stc8(ring + o3A[i] + 2, hi);
            }
        }
        __syncthreads();
    };

    // ---------- 5 groups x 4 substeps ----------
    // Parity: substeps read 0,1,0,1 -> group always ends with data in buf0,
    // and the halo import always lands in buf0.
    #pragma unroll 1
    for (int g = 0; g < NGROUPS; ++g) {
        if (g) {
            __syncthreads();   // drains ring stores (per-wave vmcnt0 before s_barrier)
            if (tid == 0)
                __hip_atomic_store(myflag, g, __ATOMIC_RELAXED, __HIP_MEMORY_SCOPE_AGENT);
            if (tid < 64) {    // wave 0, lanes 0..7 poll the 8 neighbors
                long long t0c = (long long)clock64();
                for (;;) {
                    const int v = (tid < 8)
                        ? __hip_atomic_load(nbrF, __ATOMIC_RELAXED, __HIP_MEMORY_SCOPE_AGENT)
                        : 0x7fffffff;
                    if (__all(v >= g)) break;
                    __builtin_amdgcn_s_sleep(1);
                    if ((long long)clock64() - t0c > 200000000LL) break;  // no-hang bailout
                }
            }
            __syncthreads();
            // halo import (depth 8) from ring(g-1): g-1 even -> outb, odd -> wsb
            const float* prev = ((g - 1) & 1) ? wsb : outb;
            #pragma unroll
            for (int t = 0; t < 2; ++t) {
                if (hgo[t] >= 0) {
                    const float2 lo = ldc8(prev + hgo[t]);
                    const float2 hi = ldc8(prev + hgo[t] + 2);
                    float4 v; v.x = lo.x; v.y = lo.y; v.z = hi.x; v.w = hi.y;
                    *(float4*)(sT + hlo[t]) = v;   // buf0 = current data buffer
                }
            }
            __syncthreads();
        }
        const bool lastG = (g == NGROUPS - 1);
        float* ringp = lastG ? nullptr : ((g & 1) ? wsb : outb);   // ring(g)
        substep(0, false, nullptr);
        substep(1, false, nullptr);
        substep(0, false, nullptr);
        substep(1, lastG, ringp);            // 4th substep: export ring / final tile
    }
}

extern "C" void kernel_launch(void* const* d_in, const int* in_sizes, int n_in,
                              void* d_out, int out_size, void* d_ws, size_t ws_size,
                              hipStream_t stream)
{
    const float* T    = (const float*)d_in[0];
    const float* ug   = (const float*)d_in[1];
    const float* vg   = (const float*)d_in[2];
    const float* lat  = (const float*)d_in[3];
    const float* lon  = (const float*)d_in[4];
    const float* mask = (const float*)d_in[5];
    float* out = (float*)d_out;

    int*   flags = (int*)d_ws;                        // 8 x 30 flags @ 128 B
    float* wsf   = (float*)((char*)d_ws + 65536);     // odd-group ring buffer

    hipMemsetAsync(d_ws, 0, 65536, stream);

    ocean_persist<<<dim3(XC, YC, NB), dim3(1024), 0, stream>>>(
        T, ug, vg, lat, lon, mask, out, wsf, flags);
}